// Round 18
// baseline (434.699 us; speedup 1.0000x reference)
//
#include <hip/hip_runtime.h>
#include <stdint.h>

typedef __bf16 bf16x8 __attribute__((ext_vector_type(8)));
typedef float  f32x4  __attribute__((ext_vector_type(4)));
typedef uint16_t u16x4 __attribute__((ext_vector_type(4)));

#define N_JOINT 21
#define TB 4                       // entities per tile (2 per half)
#define BATCH 16384
#define TILES 16
#define NBLK (BATCH / (TB * TILES))   // 256 blocks = 1 per CU
#define NTHREAD 512                // 8 waves x 16 cols; VGPR cap 128 (65536/512)

__device__ __forceinline__ uint32_t swz(uint32_t byteoff, uint32_t row) {
  return byteoff ^ ((row & 7u) << 4);
}
__device__ __forceinline__ uint16_t f2b(float v) {
  __bf16 b = (__bf16)v;
  return __builtin_bit_cast(uint16_t, b);
}

// zt slab: col-major [cols][64 rows] bf16, 8-row blocks rotated by col
__device__ __forceinline__ uint32_t zto(int col, int row) {
  return (uint32_t)(col * 64 + ((((row >> 3) + col) & 7) << 3) + (row & 7));
}

// ---------------- prep: weights + Lhat -> bf16 frag layouts in ws ----------------
__global__ void prep_weights(const float* __restrict__ W1, const float* __restrict__ W2,
                             const float* __restrict__ W3, uint16_t* __restrict__ ws) {
  uint16_t* wf1  = ws;
  uint16_t* wf2  = ws + 65536;
  uint16_t* wf3  = ws + 65536 + 32768;
  uint16_t* lhat = ws + 65536 + 32768 + 2048;
  for (int i = blockIdx.x * blockDim.x + threadIdx.x; i < 103424;
       i += gridDim.x * blockDim.x) {
    if (i < 65536) {
      int n = i >> 8, k = i & 255;
      float v = (n < 128) ? W1[k * 128 + n] : W1[32768 + k * 128 + (n - 128)];
      wf1[i] = f2b(v);
    } else if (i < 98304) {
      int j = i - 65536; int n = j >> 7, k = j & 127;
      float v = (n < 128) ? W2[k * 128 + n] : W2[16384 + k * 128 + (n - 128)];
      wf2[j] = f2b(v);
    } else if (i < 100352) {
      int j = i - 98304; int n = j >> 7, k = j & 127;
      float v = 0.f;
      if (n < 3)      v = W3[k * 3 + n];
      else if (n < 6) v = W3[384 + k * 3 + (n - 3)];
      wf3[j] = f2b(v);
    } else {
      // Lhat[m][k]: block-diag (2 entities x 21 joints), L = I - D^-1 (A+I)
      int j = i - 100352; int m = j >> 6, k = j & 63;
      float v = 0.f;
      if (m < 42 && k < 42 && (m / 21 == k / 21)) {
        int n = m % 21, nk = k % 21;
        float invd = (n == 0) ? (1.f / 6.f) : ((((n - 1) & 3) == 3) ? 0.5f : (1.f / 3.f));
        if (nk == n) v = 1.f - invd;
        else {
          int pn = (n > 0) ? ((((n - 1) & 3) == 0) ? 0 : n - 1) : -1;
          int pk = (nk > 0) ? ((((nk - 1) & 3) == 0) ? 0 : nk - 1) : -1;
          if (pn == nk || pk == n) v = -invd;
        }
      }
      lhat[j] = f2b(v);
    }
  }
}

#define MFMA(d, va, vb) d = __builtin_amdgcn_mfma_f32_16x16x32_bf16(va, vb, d, 0, 0, 0)

// store 4 z values for mtile mt at col c of slab base (char*)
#define ZSTORE(base, mt, v, c) { \
  u16x4 p_; p_[0] = f2b(v[0]); p_[1] = f2b(v[1]); p_[2] = f2b(v[2]); p_[3] = f2b(v[3]); \
  *(u16x4*)((base) + 2u * zto((c), mt * 16 + lk * 4)) = p_; \
}
// h = leaky(u' + bias) -> dst rows rb+mt*16+lk*4..+3, col cu (guard local row < 42)
#define HWR(dst, rb, mt, uv, bias) { \
  _Pragma("unroll") for (int rg_ = 0; rg_ < 4; ++rg_) { \
    int lr_ = mt * 16 + lk * 4 + rg_; \
    if (mt < 2 || lr_ < 42) { \
      int r_ = (rb) + lr_; \
      float h_ = uv[rg_] + bias; h_ = (h_ > 0.f) ? h_ : 0.01f * h_; \
      *(uint16_t*)(dst + swz(r_ * 256 + cu * 2, r_)) = f2b(h_); \
    } \
  } \
}
// Lhat A-frags (kc=0,1) for mtile mt from swizzled LDS copy
#define LHRD(fa, fb, mt) { \
  const int r_ = mt * 16 + l15; \
  fa = *(const bf16x8*)(lhsc + ((uint32_t)(r_ * 128 + lk * 16)      ^ ((r_ & 7u) << 4))); \
  fb = *(const bf16x8*)(lhsc + ((uint32_t)(r_ * 128 + 64 + lk * 16) ^ ((r_ & 7u) << 4))); \
}

// x tile: 84 rows x 32 octs = 2688 oct-items; sA row = r84 + 6*(r84>=42)
#define PF_ISSUE(p0, p1, j, src) { \
  const int i_ = tid + j * NTHREAD; \
  const int r_ = i_ >> 5, c8_ = (i_ & 31) * 8; \
  p0 = *(const float4*)(src + r_ * 256 + c8_); \
  p1 = *(const float4*)(src + r_ * 256 + c8_ + 4); \
}
#define PF_ISSUE_G(p0, p1, j, src) { \
  const int i_ = tid + j * NTHREAD; \
  if (i_ < 2688) { \
    const int r_ = i_ >> 5, c8_ = (i_ & 31) * 8; \
    p0 = *(const float4*)(src + r_ * 256 + c8_); \
    p1 = *(const float4*)(src + r_ * 256 + c8_ + 4); \
  } \
}
#define PF_WRITE(p0, p1, j) { \
  const int i_ = tid + j * NTHREAD; \
  const int r84_ = i_ >> 5, c8_ = (i_ & 31) * 8; \
  const int sr_ = r84_ + ((r84_ >= 42) ? 6 : 0); \
  bf16x8 o_; \
  o_[0] = (__bf16)p0.x; o_[1] = (__bf16)p0.y; o_[2] = (__bf16)p0.z; o_[3] = (__bf16)p0.w; \
  o_[4] = (__bf16)p1.x; o_[5] = (__bf16)p1.y; o_[6] = (__bf16)p1.z; o_[7] = (__bf16)p1.w; \
  *(bf16x8*)(sAc + swz(sr_ * 512 + c8_ * 2, sr_)) = o_; \
}
#define PF_WRITE_G(p0, p1, j) { \
  const int i_ = tid + j * NTHREAD; \
  if (i_ < 2688) { \
    const int r84_ = i_ >> 5, c8_ = (i_ & 31) * 8; \
    const int sr_ = r84_ + ((r84_ >= 42) ? 6 : 0); \
    bf16x8 o_; \
    o_[0] = (__bf16)p0.x; o_[1] = (__bf16)p0.y; o_[2] = (__bf16)p0.z; o_[3] = (__bf16)p0.w; \
    o_[4] = (__bf16)p1.x; o_[5] = (__bf16)p1.y; o_[6] = (__bf16)p1.z; o_[7] = (__bf16)p1.w; \
    *(bf16x8*)(sAc + swz(sr_ * 512 + c8_ * 2, sr_)) = o_; \
  } \
}

// ---------------- fused main ----------------
// R17 -> R18: REVERT to R16 (N-split waves, 157 us — R17's M/N-split
// falsified the LDS-traffic theory, regressed to 259) + one knob further in
// the winning direction: L1 chunk loop unroll 4 -> FULL (8). One load-wait
// cluster per L1 GEMM instead of two. Transient weight regs +16 (VGPR ~124).
// Spill tripwire: WRITE_SIZE must stay ~4.26 MB.
__global__ __launch_bounds__(NTHREAD)
void cheb3_main(const float* __restrict__ xp,
                const uint16_t* __restrict__ wf1, const uint16_t* __restrict__ wf2,
                const uint16_t* __restrict__ wf3, const uint16_t* __restrict__ lhp,
                const float* __restrict__ b1p, const float* __restrict__ b2p,
                const float* __restrict__ b3p, float* __restrict__ outp)
{
  __shared__ __align__(16) uint16_t sA[96 * 256];      // x bf16, swizzled (48 KB)
  __shared__ __align__(16) uint16_t sH[96 * 128];      // h1 bf16 (24 KB)
  __shared__ __align__(16) uint16_t sH2[96 * 128];     // h2 bf16 (24 KB)
  __shared__ __align__(16) uint16_t zt[2 * 128 * 64];  // z^T slabs per half (32 KB)
  __shared__ __align__(16) uint16_t zt3[2 * 16 * 64];  // z3^T slabs per half (4 KB)
  __shared__ __align__(16) uint16_t lhs[48 * 64];      // Lhat swizzled (6 KB)

  const int tid  = threadIdx.x;
  const int wid  = tid >> 6;          // 0..7
  const int w8   = wid;
  const int lane = tid & 63;
  const int l15  = lane & 15;
  const int lk   = lane >> 4;
  char* sAc  = (char*)sA;
  char* sHc  = (char*)sH;
  char* sH2c = (char*)sH2;
  char* lhsc = (char*)lhs;
  char* ztH0 = (char*)zt;
  char* ztH1 = (char*)zt + 16384;
  char* zt3c = (char*)zt3;

  const int cu = w8 * 16 + l15;       // wave's u-column block
  const float bias1 = b1p[cu];
  const float bias2 = b2p[cu];
  const float bias3 = (l15 < 3) ? b3p[l15] : 0.f;

  // init: zero zt/zt3 (rows 48..63 stay 0), pads, stage Lhat swizzled
  {
    uint4 z16 = make_uint4(0, 0, 0, 0);
    for (int i = tid; i < (2 * 128 * 64) / 8; i += NTHREAD)
      *(uint4*)((char*)zt + i * 16) = z16;
    if (tid < (2 * 16 * 64) / 8)
      *(uint4*)((char*)zt3 + tid * 16) = z16;
    if (tid < 384) {                                  // sA pads: 12 rows x 256
      int f0 = tid * 8, ri = f0 >> 8, c = f0 & 255;
      int r = 42 + ri + ((ri >= 6) ? 42 : 0);
      *(uint4*)(sAc + swz(r * 512 + c * 2, r)) = z16;
    }
    if (tid < 192) {                                  // sH/sH2 pads: 12 rows x 128
      int f0 = tid * 8, ri = f0 >> 7, c = f0 & 127;
      int r = 42 + ri + ((ri >= 6) ? 42 : 0);
      *(uint4*)(sHc + swz(r * 256 + c * 2, r)) = z16;
      *(uint4*)(sH2c + swz(r * 256 + c * 2, r)) = z16;
    }
    if (tid < 384) {                                  // lhs: 48 rows x 8 chunks
      int row = tid >> 3, c = tid & 7;
      uint4 v = *(const uint4*)(lhp + row * 64 + c * 8);
      *(uint4*)(lhsc + ((uint32_t)(row * 128 + c * 16) ^ ((row & 7u) << 4))) = v;
    }
  }

  // stage tile 0: 84 real rows (4 entities), sA row = r84 + 6*(r84>=42)
  {
    const float* xg = xp + (size_t)(blockIdx.x * TILES) * (84 * 256);
    #pragma unroll
    for (int j = 0; j < 6; ++j) {
      int i = tid + j * NTHREAD;
      if (i < 2688) {
        int r84 = i >> 5, c8 = (i & 31) * 8;
        int sr = r84 + ((r84 >= 42) ? 6 : 0);
        float4 v0 = *(const float4*)(xg + r84 * 256 + c8);
        float4 v1 = *(const float4*)(xg + r84 * 256 + c8 + 4);
        bf16x8 o;
        o[0] = (__bf16)v0.x; o[1] = (__bf16)v0.y; o[2] = (__bf16)v0.z; o[3] = (__bf16)v0.w;
        o[4] = (__bf16)v1.x; o[5] = (__bf16)v1.y; o[6] = (__bf16)v1.z; o[7] = (__bf16)v1.w;
        *(bf16x8*)(sAc + swz(sr * 512 + c8 * 2, sr)) = o;
      }
    }
  }
  __syncthreads();

  const f32x4 zero4 = {0.f, 0.f, 0.f, 0.f};

  for (int t = 0; t < TILES; ++t) {
    const int gtile = blockIdx.x * TILES + t;
    const bool pf = (t + 1 < TILES);
    const float* xn = xp + (size_t)(gtile + 1) * (84 * 256);

    // prefetch group A (j=0..2): latency hides under L1 GEMM
    float4 pA0, pA1, pA2, pA3, pA4, pA5;
    if (pf) { PF_ISSUE(pA0, pA1, 0, xn); PF_ISSUE(pA2, pA3, 1, xn); PF_ISSUE(pA4, pA5, 2, xn); }

    // ---------------- LAYER 1: sA[96][256] @ W1frag, 6 M-tiles ----------------
    f32x4 u0 = zero4, u1 = zero4, u2 = zero4, u3 = zero4, u4 = zero4, u5 = zero4;
    f32x4 z0 = zero4, z1 = zero4, z2 = zero4, z3 = zero4, z4 = zero4, z5 = zero4;
    #pragma unroll
    for (int ch = 0; ch < 8; ++ch) {
      const bf16x8 wa_ = *(const bf16x8*)(wf1 + cu * 256 + ch * 32 + lk * 8);
      const bf16x8 wb_ = *(const bf16x8*)(wf1 + (cu + 128) * 256 + ch * 32 + lk * 8);
      const int kb_ = ch * 64 + lk * 16;
      {
        const int r0_ = 0 + l15, r1_ = 16 + l15, r2_ = 32 + l15;
        bf16x8 a0_ = *(const bf16x8*)(sAc + swz(r0_ * 512 + kb_, r0_));
        bf16x8 a1_ = *(const bf16x8*)(sAc + swz(r1_ * 512 + kb_, r1_));
        bf16x8 a2_ = *(const bf16x8*)(sAc + swz(r2_ * 512 + kb_, r2_));
        MFMA(u0, a0_, wa_); MFMA(u1, a1_, wa_); MFMA(u2, a2_, wa_);
        MFMA(z0, a0_, wb_); MFMA(z1, a1_, wb_); MFMA(z2, a2_, wb_);
      }
      {
        const int r3_ = 48 + l15, r4_ = 64 + l15, r5_ = 80 + l15;
        bf16x8 a3_ = *(const bf16x8*)(sAc + swz(r3_ * 512 + kb_, r3_));
        bf16x8 a4_ = *(const bf16x8*)(sAc + swz(r4_ * 512 + kb_, r4_));
        bf16x8 a5_ = *(const bf16x8*)(sAc + swz(r5_ * 512 + kb_, r5_));
        MFMA(u3, a3_, wa_); MFMA(u4, a4_, wa_); MFMA(u5, a5_, wa_);
        MFMA(z3, a3_, wb_); MFMA(z4, a4_, wb_); MFMA(z5, a5_, wb_);
      }
    }

    // mix1: z^T -> per-half slabs (wave-private cols), u += Lhat @ z
    ZSTORE(ztH0, 0, z0, cu); ZSTORE(ztH0, 1, z1, cu); ZSTORE(ztH0, 2, z2, cu);
    ZSTORE(ztH1, 0, z3, cu); ZSTORE(ztH1, 1, z4, cu); ZSTORE(ztH1, 2, z5, cu);
    {
      bf16x8 fa, fb;
      bf16x8 bz0 = *(const bf16x8*)(ztH0 + 2u * zto(cu, 0 + lk * 8));
      bf16x8 bz1 = *(const bf16x8*)(ztH0 + 2u * zto(cu, 32 + lk * 8));
      LHRD(fa, fb, 0); MFMA(u0, fa, bz0); MFMA(u0, fb, bz1);
      LHRD(fa, fb, 1); MFMA(u1, fa, bz0); MFMA(u1, fb, bz1);
      LHRD(fa, fb, 2); MFMA(u2, fa, bz0); MFMA(u2, fb, bz1);
      bf16x8 bz2 = *(const bf16x8*)(ztH1 + 2u * zto(cu, 0 + lk * 8));
      bf16x8 bz3 = *(const bf16x8*)(ztH1 + 2u * zto(cu, 32 + lk * 8));
      LHRD(fa, fb, 0); MFMA(u3, fa, bz2); MFMA(u3, fb, bz3);
      LHRD(fa, fb, 1); MFMA(u4, fa, bz2); MFMA(u4, fb, bz3);
      LHRD(fa, fb, 2); MFMA(u5, fa, bz2); MFMA(u5, fb, bz3);
    }
    HWR(sHc, 0, 0, u0, bias1); HWR(sHc, 0, 1, u1, bias1); HWR(sHc, 0, 2, u2, bias1);
    HWR(sHc, 48, 0, u3, bias1); HWR(sHc, 48, 1, u4, bias1); HWR(sHc, 48, 2, u5, bias1);
    __syncthreads();                          // B1: h1 visible; L1 sA reads done

    // write group A into sA (dead); re-issue regs as group B (j=3..5):
    // latency hides under L2 GEMM + mix2
    if (pf) {
      PF_WRITE(pA0, pA1, 0); PF_WRITE(pA2, pA3, 1); PF_WRITE(pA4, pA5, 2);
      PF_ISSUE(pA0, pA1, 3, xn); PF_ISSUE(pA2, pA3, 4, xn); PF_ISSUE_G(pA4, pA5, 5, xn);
    }

    // ---------------- LAYER 2: sH[96][128] @ W2frag ----------------
    u0 = zero4; u1 = zero4; u2 = zero4; u3 = zero4; u4 = zero4; u5 = zero4;
    z0 = zero4; z1 = zero4; z2 = zero4; z3 = zero4; z4 = zero4; z5 = zero4;
    #pragma unroll
    for (int ch = 0; ch < 4; ++ch) {
      const bf16x8 wa_ = *(const bf16x8*)(wf2 + cu * 128 + ch * 32 + lk * 8);
      const bf16x8 wb_ = *(const bf16x8*)(wf2 + (cu + 128) * 128 + ch * 32 + lk * 8);
      const int kb_ = ch * 64 + lk * 16;
      {
        const int r0_ = 0 + l15, r1_ = 16 + l15, r2_ = 32 + l15;
        bf16x8 a0_ = *(const bf16x8*)(sHc + swz(r0_ * 256 + kb_, r0_));
        bf16x8 a1_ = *(const bf16x8*)(sHc + swz(r1_ * 256 + kb_, r1_));
        bf16x8 a2_ = *(const bf16x8*)(sHc + swz(r2_ * 256 + kb_, r2_));
        MFMA(u0, a0_, wa_); MFMA(u1, a1_, wa_); MFMA(u2, a2_, wa_);
        MFMA(z0, a0_, wb_); MFMA(z1, a1_, wb_); MFMA(z2, a2_, wb_);
      }
      {
        const int r3_ = 48 + l15, r4_ = 64 + l15, r5_ = 80 + l15;
        bf16x8 a3_ = *(const bf16x8*)(sHc + swz(r3_ * 256 + kb_, r3_));
        bf16x8 a4_ = *(const bf16x8*)(sHc + swz(r4_ * 256 + kb_, r4_));
        bf16x8 a5_ = *(const bf16x8*)(sHc + swz(r5_ * 256 + kb_, r5_));
        MFMA(u3, a3_, wa_); MFMA(u4, a4_, wa_); MFMA(u5, a5_, wa_);
        MFMA(z3, a3_, wb_); MFMA(z4, a4_, wb_); MFMA(z5, a5_, wb_);
      }
    }

    // mix2 -> sH2
    ZSTORE(ztH0, 0, z0, cu); ZSTORE(ztH0, 1, z1, cu); ZSTORE(ztH0, 2, z2, cu);
    ZSTORE(ztH1, 0, z3, cu); ZSTORE(ztH1, 1, z4, cu); ZSTORE(ztH1, 2, z5, cu);
    {
      bf16x8 fa, fb;
      bf16x8 bz0 = *(const bf16x8*)(ztH0 + 2u * zto(cu, 0 + lk * 8));
      bf16x8 bz1 = *(const bf16x8*)(ztH0 + 2u * zto(cu, 32 + lk * 8));
      LHRD(fa, fb, 0); MFMA(u0, fa, bz0); MFMA(u0, fb, bz1);
      LHRD(fa, fb, 1); MFMA(u1, fa, bz0); MFMA(u1, fb, bz1);
      LHRD(fa, fb, 2); MFMA(u2, fa, bz0); MFMA(u2, fb, bz1);
      bf16x8 bz2 = *(const bf16x8*)(ztH1 + 2u * zto(cu, 0 + lk * 8));
      bf16x8 bz3 = *(const bf16x8*)(ztH1 + 2u * zto(cu, 32 + lk * 8));
      LHRD(fa, fb, 0); MFMA(u3, fa, bz2); MFMA(u3, fb, bz3);
      LHRD(fa, fb, 1); MFMA(u4, fa, bz2); MFMA(u4, fb, bz3);
      LHRD(fa, fb, 2); MFMA(u5, fa, bz2); MFMA(u5, fb, bz3);
    }
    HWR(sH2c, 0, 0, u0, bias2); HWR(sH2c, 0, 1, u1, bias2); HWR(sH2c, 0, 2, u2, bias2);
    HWR(sH2c, 48, 0, u3, bias2); HWR(sH2c, 48, 1, u4, bias2); HWR(sH2c, 48, 2, u5, bias2);

    // write group B into sA before B2
    if (pf) { PF_WRITE(pA0, pA1, 3); PF_WRITE(pA2, pA3, 4); PF_WRITE_G(pA4, pA5, 5); }
    __syncthreads();                          // B2: h2 + fully-staged sA visible

    // ---------------- LAYER 3: two rotating waves (one per half) ----------------
    {
      const int duty = t & 7;
      if (w8 == duty || w8 == (duty ^ 1)) {
        const int h3 = (w8 == duty) ? 0 : 1;     // duty^1 differs in bit0 -> other SIMD
        char* zt3H = zt3c + h3 * 2048;
        const int rb3 = h3 * 48;
        f32x4 c30 = zero4, c31 = zero4, c32 = zero4;
        #pragma unroll 2
        for (int ch = 0; ch < 4; ++ch) {
          const bf16x8 w3_ = *(const bf16x8*)(wf3 + l15 * 128 + ch * 32 + lk * 8);
          const int kb_ = ch * 64 + lk * 16;
          const int r0_ = rb3 + l15, r1_ = rb3 + 16 + l15, r2_ = rb3 + 32 + l15;
          bf16x8 a0_ = *(const bf16x8*)(sH2c + swz(r0_ * 256 + kb_, r0_));
          bf16x8 a1_ = *(const bf16x8*)(sH2c + swz(r1_ * 256 + kb_, r1_));
          bf16x8 a2_ = *(const bf16x8*)(sH2c + swz(r2_ * 256 + kb_, r2_));
          MFMA(c30, a0_, w3_); MFMA(c31, a1_, w3_); MFMA(c32, a2_, w3_);
        }
        if (l15 >= 3 && l15 < 6) {
          ZSTORE(zt3H, 0, c30, l15 - 3); ZSTORE(zt3H, 1, c31, l15 - 3); ZSTORE(zt3H, 2, c32, l15 - 3);
        }
        {
          bf16x8 fa, fb;
          bf16x8 b30 = *(const bf16x8*)(zt3H + 2u * zto(l15, 0 + lk * 8));
          bf16x8 b31 = *(const bf16x8*)(zt3H + 2u * zto(l15, 32 + lk * 8));
          LHRD(fa, fb, 0); MFMA(c30, fa, b30); MFMA(c30, fb, b31);
          LHRD(fa, fb, 1); MFMA(c31, fa, b30); MFMA(c31, fb, b31);
          LHRD(fa, fb, 2); MFMA(c32, fa, b30); MFMA(c32, fb, b31);
        }
        if (l15 < 3) {
          #define OUT3(mt, v) { \
            const int rb_ = mt * 16 + lk * 4; \
            _Pragma("unroll") \
            for (int rg = 0; rg < 4; ++rg) { \
              int r = rb_ + rg; \
              if (r < 42) { \
                int e = r / 21, n = r - e * 21; \
                outp[((size_t)(gtile * TB + h3 * 2 + e) * N_JOINT + n) * 3 + l15] = v[rg] + bias3; \
              } \
            } \
          }
          OUT3(0, c30); OUT3(1, c31); OUT3(2, c32);
          #undef OUT3
        }
      }
    }
    // no barrier: zt/zt3 are wave-private by column/slab; L3 waves' reads
    // finish before they reach B1(t+1); next writes occur after B2(t+1).
  }
}

extern "C" void kernel_launch(void* const* d_in, const int* in_sizes, int n_in,
                              void* d_out, int out_size, void* d_ws, size_t ws_size,
                              hipStream_t stream) {
  const float* xp  = (const float*)d_in[0];
  const float* W1p = (const float*)d_in[1];
  const float* b1p = (const float*)d_in[2];
  const float* W2p = (const float*)d_in[3];
  const float* b2p = (const float*)d_in[4];
  const float* W3p = (const float*)d_in[5];
  const float* b3p = (const float*)d_in[6];
  uint16_t* ws = (uint16_t*)d_ws;

  hipLaunchKernelGGL(prep_weights, dim3(202), dim3(512), 0, stream, W1p, W2p, W3p, ws);

  const uint16_t* wf1 = ws;
  const uint16_t* wf2 = ws + 65536;
  const uint16_t* wf3 = ws + 65536 + 32768;
  const uint16_t* lhp = ws + 65536 + 32768 + 2048;
  hipLaunchKernelGGL(cheb3_main, dim3(NBLK), dim3(NTHREAD), 0, stream,
                     xp, wf1, wf2, wf3, lhp, b1p, b2p, b3p, (float*)d_out);
}

// Round 19
// 157.233 us; speedup vs baseline: 2.7647x; 2.7647x over previous
//
#include <hip/hip_runtime.h>
#include <stdint.h>

typedef __bf16 bf16x8 __attribute__((ext_vector_type(8)));
typedef float  f32x4  __attribute__((ext_vector_type(4)));
typedef uint16_t u16x4 __attribute__((ext_vector_type(4)));

#define N_JOINT 21
#define TB 4                       // entities per tile (2 per half)
#define BATCH 16384
#define TILES 16
#define NBLK (BATCH / (TB * TILES))   // 256 blocks = 1 per CU
#define NTHREAD 512                // 8 waves x 16 cols; VGPR cap 128 (65536/512)

__device__ __forceinline__ uint32_t swz(uint32_t byteoff, uint32_t row) {
  return byteoff ^ ((row & 7u) << 4);
}
__device__ __forceinline__ uint16_t f2b(float v) {
  __bf16 b = (__bf16)v;
  return __builtin_bit_cast(uint16_t, b);
}

// zt slab: col-major [cols][64 rows] bf16, 8-row blocks rotated by col
__device__ __forceinline__ uint32_t zto(int col, int row) {
  return (uint32_t)(col * 64 + ((((row >> 3) + col) & 7) << 3) + (row & 7));
}

// ---------------- prep: weights + Lhat -> bf16 frag layouts in ws ----------------
__global__ void prep_weights(const float* __restrict__ W1, const float* __restrict__ W2,
                             const float* __restrict__ W3, uint16_t* __restrict__ ws) {
  uint16_t* wf1  = ws;
  uint16_t* wf2  = ws + 65536;
  uint16_t* wf3  = ws + 65536 + 32768;
  uint16_t* lhat = ws + 65536 + 32768 + 2048;
  for (int i = blockIdx.x * blockDim.x + threadIdx.x; i < 103424;
       i += gridDim.x * blockDim.x) {
    if (i < 65536) {
      int n = i >> 8, k = i & 255;
      float v = (n < 128) ? W1[k * 128 + n] : W1[32768 + k * 128 + (n - 128)];
      wf1[i] = f2b(v);
    } else if (i < 98304) {
      int j = i - 65536; int n = j >> 7, k = j & 127;
      float v = (n < 128) ? W2[k * 128 + n] : W2[16384 + k * 128 + (n - 128)];
      wf2[j] = f2b(v);
    } else if (i < 100352) {
      int j = i - 98304; int n = j >> 7, k = j & 127;
      float v = 0.f;
      if (n < 3)      v = W3[k * 3 + n];
      else if (n < 6) v = W3[384 + k * 3 + (n - 3)];
      wf3[j] = f2b(v);
    } else {
      // Lhat[m][k]: block-diag (2 entities x 21 joints), L = I - D^-1 (A+I)
      int j = i - 100352; int m = j >> 6, k = j & 63;
      float v = 0.f;
      if (m < 42 && k < 42 && (m / 21 == k / 21)) {
        int n = m % 21, nk = k % 21;
        float invd = (n == 0) ? (1.f / 6.f) : ((((n - 1) & 3) == 3) ? 0.5f : (1.f / 3.f));
        if (nk == n) v = 1.f - invd;
        else {
          int pn = (n > 0) ? ((((n - 1) & 3) == 0) ? 0 : n - 1) : -1;
          int pk = (nk > 0) ? ((((nk - 1) & 3) == 0) ? 0 : nk - 1) : -1;
          if (pn == nk || pk == n) v = -invd;
        }
      }
      lhat[j] = f2b(v);
    }
  }
}

#define MFMA(d, va, vb) d = __builtin_amdgcn_mfma_f32_16x16x32_bf16(va, vb, d, 0, 0, 0)

// store 4 z values for mtile mt at col c of slab base (char*)
#define ZSTORE(base, mt, v, c) { \
  u16x4 p_; p_[0] = f2b(v[0]); p_[1] = f2b(v[1]); p_[2] = f2b(v[2]); p_[3] = f2b(v[3]); \
  *(u16x4*)((base) + 2u * zto((c), mt * 16 + lk * 4)) = p_; \
}
// h = leaky(u' + bias) -> dst rows rb+mt*16+lk*4..+3, col cu (guard local row < 42)
#define HWR(dst, rb, mt, uv, bias) { \
  _Pragma("unroll") for (int rg_ = 0; rg_ < 4; ++rg_) { \
    int lr_ = mt * 16 + lk * 4 + rg_; \
    if (mt < 2 || lr_ < 42) { \
      int r_ = (rb) + lr_; \
      float h_ = uv[rg_] + bias; h_ = (h_ > 0.f) ? h_ : 0.01f * h_; \
      *(uint16_t*)(dst + swz(r_ * 256 + cu * 2, r_)) = f2b(h_); \
    } \
  } \
}
// Lhat A-frags (kc=0,1) for mtile mt from swizzled LDS copy
#define LHRD(fa, fb, mt) { \
  const int r_ = mt * 16 + l15; \
  fa = *(const bf16x8*)(lhsc + ((uint32_t)(r_ * 128 + lk * 16)      ^ ((r_ & 7u) << 4))); \
  fb = *(const bf16x8*)(lhsc + ((uint32_t)(r_ * 128 + 64 + lk * 16) ^ ((r_ & 7u) << 4))); \
}

// x tile: 84 rows x 32 octs = 2688 oct-items; sA row = r84 + 6*(r84>=42)
#define PF_ISSUE(p0, p1, j, src) { \
  const int i_ = tid + j * NTHREAD; \
  const int r_ = i_ >> 5, c8_ = (i_ & 31) * 8; \
  p0 = *(const float4*)(src + r_ * 256 + c8_); \
  p1 = *(const float4*)(src + r_ * 256 + c8_ + 4); \
}
#define PF_ISSUE_G(p0, p1, j, src) { \
  const int i_ = tid + j * NTHREAD; \
  if (i_ < 2688) { \
    const int r_ = i_ >> 5, c8_ = (i_ & 31) * 8; \
    p0 = *(const float4*)(src + r_ * 256 + c8_); \
    p1 = *(const float4*)(src + r_ * 256 + c8_ + 4); \
  } \
}
#define PF_WRITE(p0, p1, j) { \
  const int i_ = tid + j * NTHREAD; \
  const int r84_ = i_ >> 5, c8_ = (i_ & 31) * 8; \
  const int sr_ = r84_ + ((r84_ >= 42) ? 6 : 0); \
  bf16x8 o_; \
  o_[0] = (__bf16)p0.x; o_[1] = (__bf16)p0.y; o_[2] = (__bf16)p0.z; o_[3] = (__bf16)p0.w; \
  o_[4] = (__bf16)p1.x; o_[5] = (__bf16)p1.y; o_[6] = (__bf16)p1.z; o_[7] = (__bf16)p1.w; \
  *(bf16x8*)(sAc + swz(sr_ * 512 + c8_ * 2, sr_)) = o_; \
}
#define PF_WRITE_G(p0, p1, j) { \
  const int i_ = tid + j * NTHREAD; \
  if (i_ < 2688) { \
    const int r84_ = i_ >> 5, c8_ = (i_ & 31) * 8; \
    const int sr_ = r84_ + ((r84_ >= 42) ? 6 : 0); \
    bf16x8 o_; \
    o_[0] = (__bf16)p0.x; o_[1] = (__bf16)p0.y; o_[2] = (__bf16)p0.z; o_[3] = (__bf16)p0.w; \
    o_[4] = (__bf16)p1.x; o_[5] = (__bf16)p1.y; o_[6] = (__bf16)p1.z; o_[7] = (__bf16)p1.w; \
    *(bf16x8*)(sAc + swz(sr_ * 512 + c8_ * 2, sr_)) = o_; \
  } \
}

// ---------------- fused main ----------------
// R18 -> R19: REVERT to R16 exactly (L1 unroll 4, L2 full — R18's full L1
// unroll hit the 128-VGPR cap and spilled 58 MB, 435 us). Plus one
// register-free lever: s_setprio(1) around the pure-MFMA mix/L3 clusters
// (T5) — waves drift between barriers here (mix is wave-local), so the
// scheduler has role diversity to arbitrate. Judged vs R16=157 us.
__global__ __launch_bounds__(NTHREAD)
void cheb3_main(const float* __restrict__ xp,
                const uint16_t* __restrict__ wf1, const uint16_t* __restrict__ wf2,
                const uint16_t* __restrict__ wf3, const uint16_t* __restrict__ lhp,
                const float* __restrict__ b1p, const float* __restrict__ b2p,
                const float* __restrict__ b3p, float* __restrict__ outp)
{
  __shared__ __align__(16) uint16_t sA[96 * 256];      // x bf16, swizzled (48 KB)
  __shared__ __align__(16) uint16_t sH[96 * 128];      // h1 bf16 (24 KB)
  __shared__ __align__(16) uint16_t sH2[96 * 128];     // h2 bf16 (24 KB)
  __shared__ __align__(16) uint16_t zt[2 * 128 * 64];  // z^T slabs per half (32 KB)
  __shared__ __align__(16) uint16_t zt3[2 * 16 * 64];  // z3^T slabs per half (4 KB)
  __shared__ __align__(16) uint16_t lhs[48 * 64];      // Lhat swizzled (6 KB)

  const int tid  = threadIdx.x;
  const int wid  = tid >> 6;          // 0..7
  const int w8   = wid;
  const int lane = tid & 63;
  const int l15  = lane & 15;
  const int lk   = lane >> 4;
  char* sAc  = (char*)sA;
  char* sHc  = (char*)sH;
  char* sH2c = (char*)sH2;
  char* lhsc = (char*)lhs;
  char* ztH0 = (char*)zt;
  char* ztH1 = (char*)zt + 16384;
  char* zt3c = (char*)zt3;

  const int cu = w8 * 16 + l15;       // wave's u-column block
  const float bias1 = b1p[cu];
  const float bias2 = b2p[cu];
  const float bias3 = (l15 < 3) ? b3p[l15] : 0.f;

  // init: zero zt/zt3 (rows 48..63 stay 0), pads, stage Lhat swizzled
  {
    uint4 z16 = make_uint4(0, 0, 0, 0);
    for (int i = tid; i < (2 * 128 * 64) / 8; i += NTHREAD)
      *(uint4*)((char*)zt + i * 16) = z16;
    if (tid < (2 * 16 * 64) / 8)
      *(uint4*)((char*)zt3 + tid * 16) = z16;
    if (tid < 384) {                                  // sA pads: 12 rows x 256
      int f0 = tid * 8, ri = f0 >> 8, c = f0 & 255;
      int r = 42 + ri + ((ri >= 6) ? 42 : 0);
      *(uint4*)(sAc + swz(r * 512 + c * 2, r)) = z16;
    }
    if (tid < 192) {                                  // sH/sH2 pads: 12 rows x 128
      int f0 = tid * 8, ri = f0 >> 7, c = f0 & 127;
      int r = 42 + ri + ((ri >= 6) ? 42 : 0);
      *(uint4*)(sHc + swz(r * 256 + c * 2, r)) = z16;
      *(uint4*)(sH2c + swz(r * 256 + c * 2, r)) = z16;
    }
    if (tid < 384) {                                  // lhs: 48 rows x 8 chunks
      int row = tid >> 3, c = tid & 7;
      uint4 v = *(const uint4*)(lhp + row * 64 + c * 8);
      *(uint4*)(lhsc + ((uint32_t)(row * 128 + c * 16) ^ ((row & 7u) << 4))) = v;
    }
  }

  // stage tile 0: 84 real rows (4 entities), sA row = r84 + 6*(r84>=42)
  {
    const float* xg = xp + (size_t)(blockIdx.x * TILES) * (84 * 256);
    #pragma unroll
    for (int j = 0; j < 6; ++j) {
      int i = tid + j * NTHREAD;
      if (i < 2688) {
        int r84 = i >> 5, c8 = (i & 31) * 8;
        int sr = r84 + ((r84 >= 42) ? 6 : 0);
        float4 v0 = *(const float4*)(xg + r84 * 256 + c8);
        float4 v1 = *(const float4*)(xg + r84 * 256 + c8 + 4);
        bf16x8 o;
        o[0] = (__bf16)v0.x; o[1] = (__bf16)v0.y; o[2] = (__bf16)v0.z; o[3] = (__bf16)v0.w;
        o[4] = (__bf16)v1.x; o[5] = (__bf16)v1.y; o[6] = (__bf16)v1.z; o[7] = (__bf16)v1.w;
        *(bf16x8*)(sAc + swz(sr * 512 + c8 * 2, sr)) = o;
      }
    }
  }
  __syncthreads();

  const f32x4 zero4 = {0.f, 0.f, 0.f, 0.f};

  for (int t = 0; t < TILES; ++t) {
    const int gtile = blockIdx.x * TILES + t;
    const bool pf = (t + 1 < TILES);
    const float* xn = xp + (size_t)(gtile + 1) * (84 * 256);

    // prefetch group A (j=0..2): latency hides under L1 GEMM
    float4 pA0, pA1, pA2, pA3, pA4, pA5;
    if (pf) { PF_ISSUE(pA0, pA1, 0, xn); PF_ISSUE(pA2, pA3, 1, xn); PF_ISSUE(pA4, pA5, 2, xn); }

    // ---------------- LAYER 1: sA[96][256] @ W1frag, 6 M-tiles ----------------
    f32x4 u0 = zero4, u1 = zero4, u2 = zero4, u3 = zero4, u4 = zero4, u5 = zero4;
    f32x4 z0 = zero4, z1 = zero4, z2 = zero4, z3 = zero4, z4 = zero4, z5 = zero4;
    #pragma unroll 4
    for (int ch = 0; ch < 8; ++ch) {
      const bf16x8 wa_ = *(const bf16x8*)(wf1 + cu * 256 + ch * 32 + lk * 8);
      const bf16x8 wb_ = *(const bf16x8*)(wf1 + (cu + 128) * 256 + ch * 32 + lk * 8);
      const int kb_ = ch * 64 + lk * 16;
      {
        const int r0_ = 0 + l15, r1_ = 16 + l15, r2_ = 32 + l15;
        bf16x8 a0_ = *(const bf16x8*)(sAc + swz(r0_ * 512 + kb_, r0_));
        bf16x8 a1_ = *(const bf16x8*)(sAc + swz(r1_ * 512 + kb_, r1_));
        bf16x8 a2_ = *(const bf16x8*)(sAc + swz(r2_ * 512 + kb_, r2_));
        MFMA(u0, a0_, wa_); MFMA(u1, a1_, wa_); MFMA(u2, a2_, wa_);
        MFMA(z0, a0_, wb_); MFMA(z1, a1_, wb_); MFMA(z2, a2_, wb_);
      }
      {
        const int r3_ = 48 + l15, r4_ = 64 + l15, r5_ = 80 + l15;
        bf16x8 a3_ = *(const bf16x8*)(sAc + swz(r3_ * 512 + kb_, r3_));
        bf16x8 a4_ = *(const bf16x8*)(sAc + swz(r4_ * 512 + kb_, r4_));
        bf16x8 a5_ = *(const bf16x8*)(sAc + swz(r5_ * 512 + kb_, r5_));
        MFMA(u3, a3_, wa_); MFMA(u4, a4_, wa_); MFMA(u5, a5_, wa_);
        MFMA(z3, a3_, wb_); MFMA(z4, a4_, wb_); MFMA(z5, a5_, wb_);
      }
    }

    // mix1: z^T -> per-half slabs (wave-private cols), u += Lhat @ z
    ZSTORE(ztH0, 0, z0, cu); ZSTORE(ztH0, 1, z1, cu); ZSTORE(ztH0, 2, z2, cu);
    ZSTORE(ztH1, 0, z3, cu); ZSTORE(ztH1, 1, z4, cu); ZSTORE(ztH1, 2, z5, cu);
    {
      bf16x8 fa, fb;
      bf16x8 bz0 = *(const bf16x8*)(ztH0 + 2u * zto(cu, 0 + lk * 8));
      bf16x8 bz1 = *(const bf16x8*)(ztH0 + 2u * zto(cu, 32 + lk * 8));
      bf16x8 bz2 = *(const bf16x8*)(ztH1 + 2u * zto(cu, 0 + lk * 8));
      bf16x8 bz3 = *(const bf16x8*)(ztH1 + 2u * zto(cu, 32 + lk * 8));
      __builtin_amdgcn_s_setprio(1);
      LHRD(fa, fb, 0); MFMA(u0, fa, bz0); MFMA(u0, fb, bz1);
      LHRD(fa, fb, 1); MFMA(u1, fa, bz0); MFMA(u1, fb, bz1);
      LHRD(fa, fb, 2); MFMA(u2, fa, bz0); MFMA(u2, fb, bz1);
      LHRD(fa, fb, 0); MFMA(u3, fa, bz2); MFMA(u3, fb, bz3);
      LHRD(fa, fb, 1); MFMA(u4, fa, bz2); MFMA(u4, fb, bz3);
      LHRD(fa, fb, 2); MFMA(u5, fa, bz2); MFMA(u5, fb, bz3);
      __builtin_amdgcn_s_setprio(0);
    }
    HWR(sHc, 0, 0, u0, bias1); HWR(sHc, 0, 1, u1, bias1); HWR(sHc, 0, 2, u2, bias1);
    HWR(sHc, 48, 0, u3, bias1); HWR(sHc, 48, 1, u4, bias1); HWR(sHc, 48, 2, u5, bias1);
    __syncthreads();                          // B1: h1 visible; L1 sA reads done

    // write group A into sA (dead); re-issue regs as group B (j=3..5):
    // latency hides under L2 GEMM + mix2
    if (pf) {
      PF_WRITE(pA0, pA1, 0); PF_WRITE(pA2, pA3, 1); PF_WRITE(pA4, pA5, 2);
      PF_ISSUE(pA0, pA1, 3, xn); PF_ISSUE(pA2, pA3, 4, xn); PF_ISSUE_G(pA4, pA5, 5, xn);
    }

    // ---------------- LAYER 2: sH[96][128] @ W2frag ----------------
    u0 = zero4; u1 = zero4; u2 = zero4; u3 = zero4; u4 = zero4; u5 = zero4;
    z0 = zero4; z1 = zero4; z2 = zero4; z3 = zero4; z4 = zero4; z5 = zero4;
    #pragma unroll
    for (int ch = 0; ch < 4; ++ch) {
      const bf16x8 wa_ = *(const bf16x8*)(wf2 + cu * 128 + ch * 32 + lk * 8);
      const bf16x8 wb_ = *(const bf16x8*)(wf2 + (cu + 128) * 128 + ch * 32 + lk * 8);
      const int kb_ = ch * 64 + lk * 16;
      {
        const int r0_ = 0 + l15, r1_ = 16 + l15, r2_ = 32 + l15;
        bf16x8 a0_ = *(const bf16x8*)(sHc + swz(r0_ * 256 + kb_, r0_));
        bf16x8 a1_ = *(const bf16x8*)(sHc + swz(r1_ * 256 + kb_, r1_));
        bf16x8 a2_ = *(const bf16x8*)(sHc + swz(r2_ * 256 + kb_, r2_));
        MFMA(u0, a0_, wa_); MFMA(u1, a1_, wa_); MFMA(u2, a2_, wa_);
        MFMA(z0, a0_, wb_); MFMA(z1, a1_, wb_); MFMA(z2, a2_, wb_);
      }
      {
        const int r3_ = 48 + l15, r4_ = 64 + l15, r5_ = 80 + l15;
        bf16x8 a3_ = *(const bf16x8*)(sHc + swz(r3_ * 256 + kb_, r3_));
        bf16x8 a4_ = *(const bf16x8*)(sHc + swz(r4_ * 256 + kb_, r4_));
        bf16x8 a5_ = *(const bf16x8*)(sHc + swz(r5_ * 256 + kb_, r5_));
        MFMA(u3, a3_, wa_); MFMA(u4, a4_, wa_); MFMA(u5, a5_, wa_);
        MFMA(z3, a3_, wb_); MFMA(z4, a4_, wb_); MFMA(z5, a5_, wb_);
      }
    }

    // mix2 -> sH2
    ZSTORE(ztH0, 0, z0, cu); ZSTORE(ztH0, 1, z1, cu); ZSTORE(ztH0, 2, z2, cu);
    ZSTORE(ztH1, 0, z3, cu); ZSTORE(ztH1, 1, z4, cu); ZSTORE(ztH1, 2, z5, cu);
    {
      bf16x8 fa, fb;
      bf16x8 bz0 = *(const bf16x8*)(ztH0 + 2u * zto(cu, 0 + lk * 8));
      bf16x8 bz1 = *(const bf16x8*)(ztH0 + 2u * zto(cu, 32 + lk * 8));
      bf16x8 bz2 = *(const bf16x8*)(ztH1 + 2u * zto(cu, 0 + lk * 8));
      bf16x8 bz3 = *(const bf16x8*)(ztH1 + 2u * zto(cu, 32 + lk * 8));
      __builtin_amdgcn_s_setprio(1);
      LHRD(fa, fb, 0); MFMA(u0, fa, bz0); MFMA(u0, fb, bz1);
      LHRD(fa, fb, 1); MFMA(u1, fa, bz0); MFMA(u1, fb, bz1);
      LHRD(fa, fb, 2); MFMA(u2, fa, bz0); MFMA(u2, fb, bz1);
      LHRD(fa, fb, 0); MFMA(u3, fa, bz2); MFMA(u3, fb, bz3);
      LHRD(fa, fb, 1); MFMA(u4, fa, bz2); MFMA(u4, fb, bz3);
      LHRD(fa, fb, 2); MFMA(u5, fa, bz2); MFMA(u5, fb, bz3);
      __builtin_amdgcn_s_setprio(0);
    }
    HWR(sH2c, 0, 0, u0, bias2); HWR(sH2c, 0, 1, u1, bias2); HWR(sH2c, 0, 2, u2, bias2);
    HWR(sH2c, 48, 0, u3, bias2); HWR(sH2c, 48, 1, u4, bias2); HWR(sH2c, 48, 2, u5, bias2);

    // write group B into sA before B2
    if (pf) { PF_WRITE(pA0, pA1, 3); PF_WRITE(pA2, pA3, 4); PF_WRITE_G(pA4, pA5, 5); }
    __syncthreads();                          // B2: h2 + fully-staged sA visible

    // ---------------- LAYER 3: two rotating waves (one per half) ----------------
    {
      const int duty = t & 7;
      if (w8 == duty || w8 == (duty ^ 1)) {
        const int h3 = (w8 == duty) ? 0 : 1;     // duty^1 differs in bit0 -> other SIMD
        char* zt3H = zt3c + h3 * 2048;
        const int rb3 = h3 * 48;
        f32x4 c30 = zero4, c31 = zero4, c32 = zero4;
        #pragma unroll 2
        for (int ch = 0; ch < 4; ++ch) {
          const bf16x8 w3_ = *(const bf16x8*)(wf3 + l15 * 128 + ch * 32 + lk * 8);
          const int kb_ = ch * 64 + lk * 16;
          const int r0_ = rb3 + l15, r1_ = rb3 + 16 + l15, r2_ = rb3 + 32 + l15;
          bf16x8 a0_ = *(const bf16x8*)(sH2c + swz(r0_ * 256 + kb_, r0_));
          bf16x8 a1_ = *(const bf16x8*)(sH2c + swz(r1_ * 256 + kb_, r1_));
          bf16x8 a2_ = *(const bf16x8*)(sH2c + swz(r2_ * 256 + kb_, r2_));
          MFMA(c30, a0_, w3_); MFMA(c31, a1_, w3_); MFMA(c32, a2_, w3_);
        }
        if (l15 >= 3 && l15 < 6) {
          ZSTORE(zt3H, 0, c30, l15 - 3); ZSTORE(zt3H, 1, c31, l15 - 3); ZSTORE(zt3H, 2, c32, l15 - 3);
        }
        {
          bf16x8 fa, fb;
          bf16x8 b30 = *(const bf16x8*)(zt3H + 2u * zto(l15, 0 + lk * 8));
          bf16x8 b31 = *(const bf16x8*)(zt3H + 2u * zto(l15, 32 + lk * 8));
          __builtin_amdgcn_s_setprio(1);
          LHRD(fa, fb, 0); MFMA(c30, fa, b30); MFMA(c30, fb, b31);
          LHRD(fa, fb, 1); MFMA(c31, fa, b30); MFMA(c31, fb, b31);
          LHRD(fa, fb, 2); MFMA(c32, fa, b30); MFMA(c32, fb, b31);
          __builtin_amdgcn_s_setprio(0);
        }
        if (l15 < 3) {
          #define OUT3(mt, v) { \
            const int rb_ = mt * 16 + lk * 4; \
            _Pragma("unroll") \
            for (int rg = 0; rg < 4; ++rg) { \
              int r = rb_ + rg; \
              if (r < 42) { \
                int e = r / 21, n = r - e * 21; \
                outp[((size_t)(gtile * TB + h3 * 2 + e) * N_JOINT + n) * 3 + l15] = v[rg] + bias3; \
              } \
            } \
          }
          OUT3(0, c30); OUT3(1, c31); OUT3(2, c32);
          #undef OUT3
        }
      }
    }
    // no barrier: zt/zt3 are wave-private by column/slab; L3 waves' reads
    // finish before they reach B1(t+1); next writes occur after B2(t+1).
  }
}

extern "C" void kernel_launch(void* const* d_in, const int* in_sizes, int n_in,
                              void* d_out, int out_size, void* d_ws, size_t ws_size,
                              hipStream_t stream) {
  const float* xp  = (const float*)d_in[0];
  const float* W1p = (const float*)d_in[1];
  const float* b1p = (const float*)d_in[2];
  const float* W2p = (const float*)d_in[3];
  const float* b2p = (const float*)d_in[4];
  const float* W3p = (const float*)d_in[5];
  const float* b3p = (const float*)d_in[6];
  uint16_t* ws = (uint16_t*)d_ws;

  hipLaunchKernelGGL(prep_weights, dim3(202), dim3(512), 0, stream, W1p, W2p, W3p, ws);

  const uint16_t* wf1 = ws;
  const uint16_t* wf2 = ws + 65536;
  const uint16_t* wf3 = ws + 65536 + 32768;
  const uint16_t* lhp = ws + 65536 + 32768 + 2048;
  hipLaunchKernelGGL(cheb3_main, dim3(NBLK), dim3(NTHREAD), 0, stream,
                     xp, wf1, wf2, wf3, lhp, b1p, b2p, b3p, (float*)d_out);
}

// Round 20
// 153.254 us; speedup vs baseline: 2.8364x; 1.0260x over previous
//
#include <hip/hip_runtime.h>
#include <stdint.h>

typedef __bf16 bf16x8 __attribute__((ext_vector_type(8)));
typedef float  f32x4  __attribute__((ext_vector_type(4)));
typedef uint16_t u16x4 __attribute__((ext_vector_type(4)));

#define N_JOINT 21
#define TB 4                       // entities per tile (2 per half)
#define BATCH 16384
#define TILES 16
#define NBLK (BATCH / (TB * TILES))   // 256 blocks = 1 per CU
#define NTHREAD 512                // 8 waves x 16 cols; VGPR cap 128 (65536/512)

__device__ __forceinline__ uint32_t swz(uint32_t byteoff, uint32_t row) {
  return byteoff ^ ((row & 7u) << 4);
}
__device__ __forceinline__ uint16_t f2b(float v) {
  __bf16 b = (__bf16)v;
  return __builtin_bit_cast(uint16_t, b);
}

// zt slab: col-major [cols][64 rows] bf16, 8-row blocks rotated by col
__device__ __forceinline__ uint32_t zto(int col, int row) {
  return (uint32_t)(col * 64 + ((((row >> 3) + col) & 7) << 3) + (row & 7));
}

// ---------------- prep: weights + Lhat -> bf16 frag layouts in ws ----------------
__global__ void prep_weights(const float* __restrict__ W1, const float* __restrict__ W2,
                             const float* __restrict__ W3, uint16_t* __restrict__ ws) {
  uint16_t* wf1  = ws;
  uint16_t* wf2  = ws + 65536;
  uint16_t* wf3  = ws + 65536 + 32768;
  uint16_t* lhat = ws + 65536 + 32768 + 2048;
  for (int i = blockIdx.x * blockDim.x + threadIdx.x; i < 103424;
       i += gridDim.x * blockDim.x) {
    if (i < 65536) {
      int n = i >> 8, k = i & 255;
      float v = (n < 128) ? W1[k * 128 + n] : W1[32768 + k * 128 + (n - 128)];
      wf1[i] = f2b(v);
    } else if (i < 98304) {
      int j = i - 65536; int n = j >> 7, k = j & 127;
      float v = (n < 128) ? W2[k * 128 + n] : W2[16384 + k * 128 + (n - 128)];
      wf2[j] = f2b(v);
    } else if (i < 100352) {
      int j = i - 98304; int n = j >> 7, k = j & 127;
      float v = 0.f;
      if (n < 3)      v = W3[k * 3 + n];
      else if (n < 6) v = W3[384 + k * 3 + (n - 3)];
      wf3[j] = f2b(v);
    } else {
      // Lhat[m][k]: block-diag (2 entities x 21 joints), L = I - D^-1 (A+I)
      int j = i - 100352; int m = j >> 6, k = j & 63;
      float v = 0.f;
      if (m < 42 && k < 42 && (m / 21 == k / 21)) {
        int n = m % 21, nk = k % 21;
        float invd = (n == 0) ? (1.f / 6.f) : ((((n - 1) & 3) == 3) ? 0.5f : (1.f / 3.f));
        if (nk == n) v = 1.f - invd;
        else {
          int pn = (n > 0) ? ((((n - 1) & 3) == 0) ? 0 : n - 1) : -1;
          int pk = (nk > 0) ? ((((nk - 1) & 3) == 0) ? 0 : nk - 1) : -1;
          if (pn == nk || pk == n) v = -invd;
        }
      }
      lhat[j] = f2b(v);
    }
  }
}

#define MFMA(d, va, vb) d = __builtin_amdgcn_mfma_f32_16x16x32_bf16(va, vb, d, 0, 0, 0)

// store 4 z values for mtile mt at col c of slab base (char*)
#define ZSTORE(base, mt, v, c) { \
  u16x4 p_; p_[0] = f2b(v[0]); p_[1] = f2b(v[1]); p_[2] = f2b(v[2]); p_[3] = f2b(v[3]); \
  *(u16x4*)((base) + 2u * zto((c), mt * 16 + lk * 4)) = p_; \
}
// h = leaky(u' + bias) -> dst rows rb+mt*16+lk*4..+3, col cu (guard local row < 42)
#define HWR(dst, rb, mt, uv, bias) { \
  _Pragma("unroll") for (int rg_ = 0; rg_ < 4; ++rg_) { \
    int lr_ = mt * 16 + lk * 4 + rg_; \
    if (mt < 2 || lr_ < 42) { \
      int r_ = (rb) + lr_; \
      float h_ = uv[rg_] + bias; h_ = (h_ > 0.f) ? h_ : 0.01f * h_; \
      *(uint16_t*)(dst + swz(r_ * 256 + cu * 2, r_)) = f2b(h_); \
    } \
  } \
}
// Lhat A-frags (kc=0,1) for mtile mt from swizzled LDS copy
#define LHRD(fa, fb, mt) { \
  const int r_ = mt * 16 + l15; \
  fa = *(const bf16x8*)(lhsc + ((uint32_t)(r_ * 128 + lk * 16)      ^ ((r_ & 7u) << 4))); \
  fb = *(const bf16x8*)(lhsc + ((uint32_t)(r_ * 128 + 64 + lk * 16) ^ ((r_ & 7u) << 4))); \
}

// x tile: 84 rows x 32 octs = 2688 oct-items; sA row = r84 + 6*(r84>=42)
#define PF_ISSUE(p0, p1, j, src) { \
  const int i_ = tid + j * NTHREAD; \
  const int r_ = i_ >> 5, c8_ = (i_ & 31) * 8; \
  p0 = *(const float4*)(src + r_ * 256 + c8_); \
  p1 = *(const float4*)(src + r_ * 256 + c8_ + 4); \
}
#define PF_ISSUE_G(p0, p1, j, src) { \
  const int i_ = tid + j * NTHREAD; \
  if (i_ < 2688) { \
    const int r_ = i_ >> 5, c8_ = (i_ & 31) * 8; \
    p0 = *(const float4*)(src + r_ * 256 + c8_); \
    p1 = *(const float4*)(src + r_ * 256 + c8_ + 4); \
  } \
}
#define PF_WRITE(p0, p1, j) { \
  const int i_ = tid + j * NTHREAD; \
  const int r84_ = i_ >> 5, c8_ = (i_ & 31) * 8; \
  const int sr_ = r84_ + ((r84_ >= 42) ? 6 : 0); \
  bf16x8 o_; \
  o_[0] = (__bf16)p0.x; o_[1] = (__bf16)p0.y; o_[2] = (__bf16)p0.z; o_[3] = (__bf16)p0.w; \
  o_[4] = (__bf16)p1.x; o_[5] = (__bf16)p1.y; o_[6] = (__bf16)p1.z; o_[7] = (__bf16)p1.w; \
  *(bf16x8*)(sAc + swz(sr_ * 512 + c8_ * 2, sr_)) = o_; \
}
#define PF_WRITE_G(p0, p1, j) { \
  const int i_ = tid + j * NTHREAD; \
  if (i_ < 2688) { \
    const int r84_ = i_ >> 5, c8_ = (i_ & 31) * 8; \
    const int sr_ = r84_ + ((r84_ >= 42) ? 6 : 0); \
    bf16x8 o_; \
    o_[0] = (__bf16)p0.x; o_[1] = (__bf16)p0.y; o_[2] = (__bf16)p0.z; o_[3] = (__bf16)p0.w; \
    o_[4] = (__bf16)p1.x; o_[5] = (__bf16)p1.y; o_[6] = (__bf16)p1.z; o_[7] = (__bf16)p1.w; \
    *(bf16x8*)(sAc + swz(sr_ * 512 + c8_ * 2, sr_)) = o_; \
  } \
}

// ---------------- fused main ----------------
// R19 -> R20: vmcnt is ORDINAL — HBM prefetch loads issued before the GEMM's
// L2-hit weight loads make every weight wait drain the HBM loads first.
// Fix: PF_ISSUE group A moves AFTER the L1 chunk loop; group B moves AFTER
// the L2 chunk loop (weight loads now head the VMEM queue; pA loads complete
// under mix+HWR+barrier-drain). Plus: W2 chunk-0 frag pair persistent in
// registers (16 regs, loaded once) — L2 GEMM ch=0 peeled, head wait removed.
// VGPR ~124; spill tripwire: WRITE_SIZE must stay ~4.26 MB.
__global__ __launch_bounds__(NTHREAD)
void cheb3_main(const float* __restrict__ xp,
                const uint16_t* __restrict__ wf1, const uint16_t* __restrict__ wf2,
                const uint16_t* __restrict__ wf3, const uint16_t* __restrict__ lhp,
                const float* __restrict__ b1p, const float* __restrict__ b2p,
                const float* __restrict__ b3p, float* __restrict__ outp)
{
  __shared__ __align__(16) uint16_t sA[96 * 256];      // x bf16, swizzled (48 KB)
  __shared__ __align__(16) uint16_t sH[96 * 128];      // h1 bf16 (24 KB)
  __shared__ __align__(16) uint16_t sH2[96 * 128];     // h2 bf16 (24 KB)
  __shared__ __align__(16) uint16_t zt[2 * 128 * 64];  // z^T slabs per half (32 KB)
  __shared__ __align__(16) uint16_t zt3[2 * 16 * 64];  // z3^T slabs per half (4 KB)
  __shared__ __align__(16) uint16_t lhs[48 * 64];      // Lhat swizzled (6 KB)

  const int tid  = threadIdx.x;
  const int wid  = tid >> 6;          // 0..7
  const int w8   = wid;
  const int lane = tid & 63;
  const int l15  = lane & 15;
  const int lk   = lane >> 4;
  char* sAc  = (char*)sA;
  char* sHc  = (char*)sH;
  char* sH2c = (char*)sH2;
  char* lhsc = (char*)lhs;
  char* ztH0 = (char*)zt;
  char* ztH1 = (char*)zt + 16384;
  char* zt3c = (char*)zt3;

  const int cu = w8 * 16 + l15;       // wave's u-column block
  const float bias1 = b1p[cu];
  const float bias2 = b2p[cu];
  const float bias3 = (l15 < 3) ? b3p[l15] : 0.f;

  // persistent W2 chunk-0 fragment pair (16 VGPR, tile-invariant)
  const bf16x8 w2p0a = *(const bf16x8*)(wf2 + cu * 128 + lk * 8);
  const bf16x8 w2p0b = *(const bf16x8*)(wf2 + (cu + 128) * 128 + lk * 8);

  // init: zero zt/zt3 (rows 48..63 stay 0), pads, stage Lhat swizzled
  {
    uint4 z16 = make_uint4(0, 0, 0, 0);
    for (int i = tid; i < (2 * 128 * 64) / 8; i += NTHREAD)
      *(uint4*)((char*)zt + i * 16) = z16;
    if (tid < (2 * 16 * 64) / 8)
      *(uint4*)((char*)zt3 + tid * 16) = z16;
    if (tid < 384) {                                  // sA pads: 12 rows x 256
      int f0 = tid * 8, ri = f0 >> 8, c = f0 & 255;
      int r = 42 + ri + ((ri >= 6) ? 42 : 0);
      *(uint4*)(sAc + swz(r * 512 + c * 2, r)) = z16;
    }
    if (tid < 192) {                                  // sH/sH2 pads: 12 rows x 128
      int f0 = tid * 8, ri = f0 >> 7, c = f0 & 127;
      int r = 42 + ri + ((ri >= 6) ? 42 : 0);
      *(uint4*)(sHc + swz(r * 256 + c * 2, r)) = z16;
      *(uint4*)(sH2c + swz(r * 256 + c * 2, r)) = z16;
    }
    if (tid < 384) {                                  // lhs: 48 rows x 8 chunks
      int row = tid >> 3, c = tid & 7;
      uint4 v = *(const uint4*)(lhp + row * 64 + c * 8);
      *(uint4*)(lhsc + ((uint32_t)(row * 128 + c * 16) ^ ((row & 7u) << 4))) = v;
    }
  }

  // stage tile 0: 84 real rows (4 entities), sA row = r84 + 6*(r84>=42)
  {
    const float* xg = xp + (size_t)(blockIdx.x * TILES) * (84 * 256);
    #pragma unroll
    for (int j = 0; j < 6; ++j) {
      int i = tid + j * NTHREAD;
      if (i < 2688) {
        int r84 = i >> 5, c8 = (i & 31) * 8;
        int sr = r84 + ((r84 >= 42) ? 6 : 0);
        float4 v0 = *(const float4*)(xg + r84 * 256 + c8);
        float4 v1 = *(const float4*)(xg + r84 * 256 + c8 + 4);
        bf16x8 o;
        o[0] = (__bf16)v0.x; o[1] = (__bf16)v0.y; o[2] = (__bf16)v0.z; o[3] = (__bf16)v0.w;
        o[4] = (__bf16)v1.x; o[5] = (__bf16)v1.y; o[6] = (__bf16)v1.z; o[7] = (__bf16)v1.w;
        *(bf16x8*)(sAc + swz(sr * 512 + c8 * 2, sr)) = o;
      }
    }
  }
  __syncthreads();

  const f32x4 zero4 = {0.f, 0.f, 0.f, 0.f};

  for (int t = 0; t < TILES; ++t) {
    const int gtile = blockIdx.x * TILES + t;
    const bool pf = (t + 1 < TILES);
    const float* xn = xp + (size_t)(gtile + 1) * (84 * 256);
    float4 pA0, pA1, pA2, pA3, pA4, pA5;

    // ---------------- LAYER 1: sA[96][256] @ W1frag, 6 M-tiles ----------------
    // (weight loads head the VMEM queue this tile — no HBM loads in front)
    f32x4 u0 = zero4, u1 = zero4, u2 = zero4, u3 = zero4, u4 = zero4, u5 = zero4;
    f32x4 z0 = zero4, z1 = zero4, z2 = zero4, z3 = zero4, z4 = zero4, z5 = zero4;
    #pragma unroll 4
    for (int ch = 0; ch < 8; ++ch) {
      const bf16x8 wa_ = *(const bf16x8*)(wf1 + cu * 256 + ch * 32 + lk * 8);
      const bf16x8 wb_ = *(const bf16x8*)(wf1 + (cu + 128) * 256 + ch * 32 + lk * 8);
      const int kb_ = ch * 64 + lk * 16;
      {
        const int r0_ = 0 + l15, r1_ = 16 + l15, r2_ = 32 + l15;
        bf16x8 a0_ = *(const bf16x8*)(sAc + swz(r0_ * 512 + kb_, r0_));
        bf16x8 a1_ = *(const bf16x8*)(sAc + swz(r1_ * 512 + kb_, r1_));
        bf16x8 a2_ = *(const bf16x8*)(sAc + swz(r2_ * 512 + kb_, r2_));
        MFMA(u0, a0_, wa_); MFMA(u1, a1_, wa_); MFMA(u2, a2_, wa_);
        MFMA(z0, a0_, wb_); MFMA(z1, a1_, wb_); MFMA(z2, a2_, wb_);
      }
      {
        const int r3_ = 48 + l15, r4_ = 64 + l15, r5_ = 80 + l15;
        bf16x8 a3_ = *(const bf16x8*)(sAc + swz(r3_ * 512 + kb_, r3_));
        bf16x8 a4_ = *(const bf16x8*)(sAc + swz(r4_ * 512 + kb_, r4_));
        bf16x8 a5_ = *(const bf16x8*)(sAc + swz(r5_ * 512 + kb_, r5_));
        MFMA(u3, a3_, wa_); MFMA(u4, a4_, wa_); MFMA(u5, a5_, wa_);
        MFMA(z3, a3_, wb_); MFMA(z4, a4_, wb_); MFMA(z5, a5_, wb_);
      }
    }

    // prefetch group A AFTER the weight loads: completes under mix1/HWR/B1
    if (pf) { PF_ISSUE(pA0, pA1, 0, xn); PF_ISSUE(pA2, pA3, 1, xn); PF_ISSUE(pA4, pA5, 2, xn); }

    // mix1: z^T -> per-half slabs (wave-private cols), u += Lhat @ z
    ZSTORE(ztH0, 0, z0, cu); ZSTORE(ztH0, 1, z1, cu); ZSTORE(ztH0, 2, z2, cu);
    ZSTORE(ztH1, 0, z3, cu); ZSTORE(ztH1, 1, z4, cu); ZSTORE(ztH1, 2, z5, cu);
    {
      bf16x8 fa, fb;
      bf16x8 bz0 = *(const bf16x8*)(ztH0 + 2u * zto(cu, 0 + lk * 8));
      bf16x8 bz1 = *(const bf16x8*)(ztH0 + 2u * zto(cu, 32 + lk * 8));
      bf16x8 bz2 = *(const bf16x8*)(ztH1 + 2u * zto(cu, 0 + lk * 8));
      bf16x8 bz3 = *(const bf16x8*)(ztH1 + 2u * zto(cu, 32 + lk * 8));
      __builtin_amdgcn_s_setprio(1);
      LHRD(fa, fb, 0); MFMA(u0, fa, bz0); MFMA(u0, fb, bz1);
      LHRD(fa, fb, 1); MFMA(u1, fa, bz0); MFMA(u1, fb, bz1);
      LHRD(fa, fb, 2); MFMA(u2, fa, bz0); MFMA(u2, fb, bz1);
      LHRD(fa, fb, 0); MFMA(u3, fa, bz2); MFMA(u3, fb, bz3);
      LHRD(fa, fb, 1); MFMA(u4, fa, bz2); MFMA(u4, fb, bz3);
      LHRD(fa, fb, 2); MFMA(u5, fa, bz2); MFMA(u5, fb, bz3);
      __builtin_amdgcn_s_setprio(0);
    }
    HWR(sHc, 0, 0, u0, bias1); HWR(sHc, 0, 1, u1, bias1); HWR(sHc, 0, 2, u2, bias1);
    HWR(sHc, 48, 0, u3, bias1); HWR(sHc, 48, 1, u4, bias1); HWR(sHc, 48, 2, u5, bias1);
    __syncthreads();                          // B1: h1 visible; L1 sA reads done

    // write group A into sA (dead zone)
    if (pf) { PF_WRITE(pA0, pA1, 0); PF_WRITE(pA2, pA3, 1); PF_WRITE(pA4, pA5, 2); }

    // ---------------- LAYER 2: sH[96][128] @ W2frag ----------------
    u0 = zero4; u1 = zero4; u2 = zero4; u3 = zero4; u4 = zero4; u5 = zero4;
    z0 = zero4; z1 = zero4; z2 = zero4; z3 = zero4; z4 = zero4; z5 = zero4;
    // ch = 0 peeled with persistent w2p0a/b (no head wait)
    {
      const int kb_ = lk * 16;
      {
        const int r0_ = 0 + l15, r1_ = 16 + l15, r2_ = 32 + l15;
        bf16x8 a0_ = *(const bf16x8*)(sHc + swz(r0_ * 256 + kb_, r0_));
        bf16x8 a1_ = *(const bf16x8*)(sHc + swz(r1_ * 256 + kb_, r1_));
        bf16x8 a2_ = *(const bf16x8*)(sHc + swz(r2_ * 256 + kb_, r2_));
        MFMA(u0, a0_, w2p0a); MFMA(u1, a1_, w2p0a); MFMA(u2, a2_, w2p0a);
        MFMA(z0, a0_, w2p0b); MFMA(z1, a1_, w2p0b); MFMA(z2, a2_, w2p0b);
      }
      {
        const int r3_ = 48 + l15, r4_ = 64 + l15, r5_ = 80 + l15;
        bf16x8 a3_ = *(const bf16x8*)(sHc + swz(r3_ * 256 + kb_, r3_));
        bf16x8 a4_ = *(const bf16x8*)(sHc + swz(r4_ * 256 + kb_, r4_));
        bf16x8 a5_ = *(const bf16x8*)(sHc + swz(r5_ * 256 + kb_, r5_));
        MFMA(u3, a3_, w2p0a); MFMA(u4, a4_, w2p0a); MFMA(u5, a5_, w2p0a);
        MFMA(z3, a3_, w2p0b); MFMA(z4, a4_, w2p0b); MFMA(z5, a5_, w2p0b);
      }
    }
    #pragma unroll
    for (int ch = 1; ch < 4; ++ch) {
      const bf16x8 wa_ = *(const bf16x8*)(wf2 + cu * 128 + ch * 32 + lk * 8);
      const bf16x8 wb_ = *(const bf16x8*)(wf2 + (cu + 128) * 128 + ch * 32 + lk * 8);
      const int kb_ = ch * 64 + lk * 16;
      {
        const int r0_ = 0 + l15, r1_ = 16 + l15, r2_ = 32 + l15;
        bf16x8 a0_ = *(const bf16x8*)(sHc + swz(r0_ * 256 + kb_, r0_));
        bf16x8 a1_ = *(const bf16x8*)(sHc + swz(r1_ * 256 + kb_, r1_));
        bf16x8 a2_ = *(const bf16x8*)(sHc + swz(r2_ * 256 + kb_, r2_));
        MFMA(u0, a0_, wa_); MFMA(u1, a1_, wa_); MFMA(u2, a2_, wa_);
        MFMA(z0, a0_, wb_); MFMA(z1, a1_, wb_); MFMA(z2, a2_, wb_);
      }
      {
        const int r3_ = 48 + l15, r4_ = 64 + l15, r5_ = 80 + l15;
        bf16x8 a3_ = *(const bf16x8*)(sHc + swz(r3_ * 256 + kb_, r3_));
        bf16x8 a4_ = *(const bf16x8*)(sHc + swz(r4_ * 256 + kb_, r4_));
        bf16x8 a5_ = *(const bf16x8*)(sHc + swz(r5_ * 256 + kb_, r5_));
        MFMA(u3, a3_, wa_); MFMA(u4, a4_, wa_); MFMA(u5, a5_, wa_);
        MFMA(z3, a3_, wb_); MFMA(z4, a4_, wb_); MFMA(z5, a5_, wb_);
      }
    }

    // prefetch group B AFTER L2's weight loads: completes under mix2/HWR/B2
    if (pf) { PF_ISSUE(pA0, pA1, 3, xn); PF_ISSUE(pA2, pA3, 4, xn); PF_ISSUE_G(pA4, pA5, 5, xn); }

    // mix2 -> sH2
    ZSTORE(ztH0, 0, z0, cu); ZSTORE(ztH0, 1, z1, cu); ZSTORE(ztH0, 2, z2, cu);
    ZSTORE(ztH1, 0, z3, cu); ZSTORE(ztH1, 1, z4, cu); ZSTORE(ztH1, 2, z5, cu);
    {
      bf16x8 fa, fb;
      bf16x8 bz0 = *(const bf16x8*)(ztH0 + 2u * zto(cu, 0 + lk * 8));
      bf16x8 bz1 = *(const bf16x8*)(ztH0 + 2u * zto(cu, 32 + lk * 8));
      bf16x8 bz2 = *(const bf16x8*)(ztH1 + 2u * zto(cu, 0 + lk * 8));
      bf16x8 bz3 = *(const bf16x8*)(ztH1 + 2u * zto(cu, 32 + lk * 8));
      __builtin_amdgcn_s_setprio(1);
      LHRD(fa, fb, 0); MFMA(u0, fa, bz0); MFMA(u0, fb, bz1);
      LHRD(fa, fb, 1); MFMA(u1, fa, bz0); MFMA(u1, fb, bz1);
      LHRD(fa, fb, 2); MFMA(u2, fa, bz0); MFMA(u2, fb, bz1);
      LHRD(fa, fb, 0); MFMA(u3, fa, bz2); MFMA(u3, fb, bz3);
      LHRD(fa, fb, 1); MFMA(u4, fa, bz2); MFMA(u4, fb, bz3);
      LHRD(fa, fb, 2); MFMA(u5, fa, bz2); MFMA(u5, fb, bz3);
      __builtin_amdgcn_s_setprio(0);
    }
    HWR(sH2c, 0, 0, u0, bias2); HWR(sH2c, 0, 1, u1, bias2); HWR(sH2c, 0, 2, u2, bias2);
    HWR(sH2c, 48, 0, u3, bias2); HWR(sH2c, 48, 1, u4, bias2); HWR(sH2c, 48, 2, u5, bias2);

    // write group B into sA before B2
    if (pf) { PF_WRITE(pA0, pA1, 3); PF_WRITE(pA2, pA3, 4); PF_WRITE_G(pA4, pA5, 5); }
    __syncthreads();                          // B2: h2 + fully-staged sA visible

    // ---------------- LAYER 3: two rotating waves (one per half) ----------------
    {
      const int duty = t & 7;
      if (w8 == duty || w8 == (duty ^ 1)) {
        const int h3 = (w8 == duty) ? 0 : 1;     // duty^1 differs in bit0 -> other SIMD
        char* zt3H = zt3c + h3 * 2048;
        const int rb3 = h3 * 48;
        f32x4 c30 = zero4, c31 = zero4, c32 = zero4;
        #pragma unroll 2
        for (int ch = 0; ch < 4; ++ch) {
          const bf16x8 w3_ = *(const bf16x8*)(wf3 + l15 * 128 + ch * 32 + lk * 8);
          const int kb_ = ch * 64 + lk * 16;
          const int r0_ = rb3 + l15, r1_ = rb3 + 16 + l15, r2_ = rb3 + 32 + l15;
          bf16x8 a0_ = *(const bf16x8*)(sH2c + swz(r0_ * 256 + kb_, r0_));
          bf16x8 a1_ = *(const bf16x8*)(sH2c + swz(r1_ * 256 + kb_, r1_));
          bf16x8 a2_ = *(const bf16x8*)(sH2c + swz(r2_ * 256 + kb_, r2_));
          MFMA(c30, a0_, w3_); MFMA(c31, a1_, w3_); MFMA(c32, a2_, w3_);
        }
        if (l15 >= 3 && l15 < 6) {
          ZSTORE(zt3H, 0, c30, l15 - 3); ZSTORE(zt3H, 1, c31, l15 - 3); ZSTORE(zt3H, 2, c32, l15 - 3);
        }
        {
          bf16x8 fa, fb;
          bf16x8 b30 = *(const bf16x8*)(zt3H + 2u * zto(l15, 0 + lk * 8));
          bf16x8 b31 = *(const bf16x8*)(zt3H + 2u * zto(l15, 32 + lk * 8));
          __builtin_amdgcn_s_setprio(1);
          LHRD(fa, fb, 0); MFMA(c30, fa, b30); MFMA(c30, fb, b31);
          LHRD(fa, fb, 1); MFMA(c31, fa, b30); MFMA(c31, fb, b31);
          LHRD(fa, fb, 2); MFMA(c32, fa, b30); MFMA(c32, fb, b31);
          __builtin_amdgcn_s_setprio(0);
        }
        if (l15 < 3) {
          #define OUT3(mt, v) { \
            const int rb_ = mt * 16 + lk * 4; \
            _Pragma("unroll") \
            for (int rg = 0; rg < 4; ++rg) { \
              int r = rb_ + rg; \
              if (r < 42) { \
                int e = r / 21, n = r - e * 21; \
                outp[((size_t)(gtile * TB + h3 * 2 + e) * N_JOINT + n) * 3 + l15] = v[rg] + bias3; \
              } \
            } \
          }
          OUT3(0, c30); OUT3(1, c31); OUT3(2, c32);
          #undef OUT3
        }
      }
    }
    // no barrier: zt/zt3 are wave-private by column/slab; L3 waves' reads
    // finish before they reach B1(t+1); next writes occur after B2(t+1).
  }
}

extern "C" void kernel_launch(void* const* d_in, const int* in_sizes, int n_in,
                              void* d_out, int out_size, void* d_ws, size_t ws_size,
                              hipStream_t stream) {
  const float* xp  = (const float*)d_in[0];
  const float* W1p = (const float*)d_in[1];
  const float* b1p = (const float*)d_in[2];
  const float* W2p = (const float*)d_in[3];
  const float* b2p = (const float*)d_in[4];
  const float* W3p = (const float*)d_in[5];
  const float* b3p = (const float*)d_in[6];
  uint16_t* ws = (uint16_t*)d_ws;

  hipLaunchKernelGGL(prep_weights, dim3(202), dim3(512), 0, stream, W1p, W2p, W3p, ws);

  const uint16_t* wf1 = ws;
  const uint16_t* wf2 = ws + 65536;
  const uint16_t* wf3 = ws + 65536 + 32768;
  const uint16_t* lhp = ws + 65536 + 32768 + 2048;
  hipLaunchKernelGGL(cheb3_main, dim3(NBLK), dim3(NTHREAD), 0, stream,
                     xp, wf1, wf2, wf3, lhp, b1p, b2p, b3p, (float*)d_out);
}